// Round 1
// baseline (4218.146 us; speedup 1.0000x reference)
//
#include <hip/hip_runtime.h>

typedef _Float16 half8 __attribute__((ext_vector_type(8)));
typedef float floatx16 __attribute__((ext_vector_type(16)));

#define MFMA16(a,b,c) __builtin_amdgcn_mfma_f32_32x32x16_f16((a),(b),(c),0,0,0)

// fp16 weight workspace layout (element offsets)
#define O_D0 0
#define N_D0 768
#define O_DC (O_D0 + N_D0)      // 768
#define N_DC 196608
#define O_PX (O_DC + N_DC)      // 197376
#define N_PX 65536
#define O_C1 (O_PX + N_PX)      // 262912
#define O_C2 (O_C1 + 16384)     // 279296
#define O_F  (O_C2 + 16384)     // 295680
#define W_TOTAL (O_F + 8192)    // 303872 elements

__global__ void wconv_kernel(const float* __restrict__ w_d0, const float* __restrict__ w_dc,
                             const float* __restrict__ w_px, const float* __restrict__ w_c1,
                             const float* __restrict__ w_c2, const float* __restrict__ w_f,
                             _Float16* __restrict__ ws) {
  int i = blockIdx.x * 256 + threadIdx.x;
  if (i >= W_TOTAL) return;
  float v;
  if (i < O_PX)       { if (i < O_DC) v = w_d0[i]; else v = w_dc[i - O_DC]; }
  else if (i < O_C1)  v = w_px[i - O_PX];
  else if (i < O_C2)  v = w_c1[i - O_C1];
  else if (i < O_F)   v = w_c2[i - O_C2];
  else                v = w_f[i - O_F];
  ws[i] = (_Float16)v;
}

__device__ __forceinline__ float silu_f(float v) {
  return v / (1.0f + __expf(-v));
}

// swizzled LDS element offset for [pixel][128ch] fp16 tiles
__device__ __forceinline__ int loff(int p, int k) {
  return p * 128 + (k ^ ((p & 15) << 3));
}

__device__ __forceinline__ floatx16 zero16() {
  floatx16 z;
#pragma unroll
  for (int i = 0; i < 16; ++i) z[i] = 0.0f;
  return z;
}

// GEMM: out[f][c] = sum_t sum_k A[f + sh_t][k] * wq[t*NROWS + c][k]
// A from LDS (swizzled), weights fp16 from global.
// 8 waves: mg in 0..3 -> m-tiles {2mg,2mg+1} (32 px each), ng in 0..1 -> NT n-tiles.
template<int TAPS, int NT>
__device__ __forceinline__ void run_gemm(
    const _Float16* asrc, int abase, int sh0, int sh2,
    const _Float16* __restrict__ wq,
    int mg, int ng, int lrow, int lk8,
    floatx16 acc[2][2])
{
  const int NROWS = NT * 64;
  const int sh[3] = {sh0, 0, sh2};
  int pb[TAPS][2], psw[TAPS][2];
  const _Float16* wp[TAPS][NT];
#pragma unroll
  for (int t = 0; t < TAPS; ++t) {
#pragma unroll
    for (int mm = 0; mm < 2; ++mm) {
      int p = abase + (2 * mg + mm) * 32 + lrow + (TAPS == 3 ? sh[t] : 0);
      pb[t][mm] = p * 128;
      psw[t][mm] = (p & 15) << 3;
    }
#pragma unroll
    for (int nn = 0; nn < NT; ++nn) {
      int c = (NT == 2 ? (2 * ng + nn) : ng) * 32 + lrow;
      wp[t][nn] = wq + (t * NROWS + c) * 128 + lk8;
    }
  }
#pragma unroll
  for (int mm = 0; mm < 2; ++mm)
#pragma unroll
    for (int nn = 0; nn < NT; ++nn)
      acc[mm][nn] = zero16();

#pragma unroll
  for (int kk = 0; kk < 8; ++kk) {
    const int k = kk * 16 + lk8;
    half8 bf[TAPS][NT], af[TAPS][2];
#pragma unroll
    for (int t = 0; t < TAPS; ++t)
#pragma unroll
      for (int nn = 0; nn < NT; ++nn)
        bf[t][nn] = *(const half8*)(wp[t][nn] + kk * 16);
#pragma unroll
    for (int t = 0; t < TAPS; ++t)
#pragma unroll
      for (int mm = 0; mm < 2; ++mm)
        af[t][mm] = *(const half8*)&asrc[pb[t][mm] + (k ^ psw[t][mm])];
#pragma unroll
    for (int t = 0; t < TAPS; ++t)
#pragma unroll
      for (int mm = 0; mm < 2; ++mm)
#pragma unroll
        for (int nn = 0; nn < NT; ++nn)
          acc[mm][nn] = MFMA16(af[t][mm], bf[t][nn], acc[mm][nn]);
  }
}

__global__ __launch_bounds__(512, 2) void mixnet_kernel(
    const float* __restrict__ xin, const _Float16* __restrict__ ws,
    const float* __restrict__ b_d0, const float* __restrict__ b_dc,
    const float* __restrict__ b_px, const float* __restrict__ b_c1,
    const float* __restrict__ b_c2, const float* __restrict__ b_f,
    float* __restrict__ out)
{
  // A: padded activation buffer, pixel addr pa = f + 17, pa in [0,290)
  __shared__ _Float16 Ab[290 * 128];   // 74240 B
  __shared__ _Float16 Bb[256 * 128];   // 65536 B

  const int bid = blockIdx.x;
  const int b = bid >> 2, d = bid & 3;
  const int tid = threadIdx.x;
  const int wv = tid >> 6, l = tid & 63;
  const int mg = wv >> 1, ng = wv & 1;
  const int lrow = l & 31;
  const int lk8 = (l >> 5) << 3;
  const int lhalf = l >> 5;

  static const int DYT[4][3] = {{0,0,0},{-1,0,1},{-1,0,1},{1,0,-1}};
  static const int DXT[4][3] = {{-1,0,1},{0,0,0},{-1,0,1},{-1,0,1}};
  const int sh0 = DYT[d][0] * 16 + DXT[d][0];
  const int sh2 = DYT[d][2] * 16 + DXT[d][2];

  // ---- zero A buffer (pads must stay 0 forever) ----
  {
    int* Ai = (int*)Ab;
    for (int i = tid; i < 290 * 128 / 2; i += 512) Ai[i] = 0;
  }
  // ---- staging for initial conv in B region: Axt[256][16], wBs[128][16] ----
  _Float16* Axt = Bb;          // 4096 halves
  _Float16* wBs = Bb + 4096;   // 2048 halves
  {
    int* Bi = (int*)Bb;
    for (int i = tid; i < (4096 + 2048) / 2; i += 512) Bi[i] = 0;
  }
  __syncthreads();
  // gather shifted x into Axt: k = t*2 + ci, zero outside image
  for (int i = tid; i < 256 * 6; i += 512) {
    int f = i / 6, k = i % 6, t = k >> 1, ci = k & 1;
    int y = (f >> 4) - 1 + DYT[d][t];
    int xx = (f & 15) + DXT[d][t];
    float v = 0.0f;
    if (y >= 0 && y < 15 && xx >= 0 && xx < 15)
      v = xin[b * 450 + ci * 225 + y * 15 + xx];
    Axt[f * 16 + k] = (_Float16)v;
  }
  for (int i = tid; i < 128 * 6; i += 512) {
    int c = i / 6, k = i % 6, t = k >> 1, ci = k & 1;
    wBs[c * 16 + k] = ws[O_D0 + (t * 128 + c) * 2 + ci];
  }
  __syncthreads();

  // ---- initial dirconv via one K=16 MFMA step; fp32 residual lives in regs ----
  float xres[2][2][16];
  {
    half8 af[2], bf[2];
#pragma unroll
    for (int mm = 0; mm < 2; ++mm) {
      int p = (2 * mg + mm) * 32 + lrow;
      af[mm] = *(const half8*)&Axt[p * 16 + lk8];
    }
#pragma unroll
    for (int nn = 0; nn < 2; ++nn) {
      int c = (2 * ng + nn) * 32 + lrow;
      bf[nn] = *(const half8*)&wBs[c * 16 + lk8];
    }
    floatx16 acc0[2][2];
#pragma unroll
    for (int mm = 0; mm < 2; ++mm)
#pragma unroll
      for (int nn = 0; nn < 2; ++nn) {
        acc0[mm][nn] = zero16();
        acc0[mm][nn] = MFMA16(af[mm], bf[nn], acc0[mm][nn]);
      }
#pragma unroll
    for (int mm = 0; mm < 2; ++mm)
#pragma unroll
      for (int nn = 0; nn < 2; ++nn) {
        int c = (2 * ng + nn) * 32 + lrow;
        float bias = b_d0[c];
#pragma unroll
        for (int j = 0; j < 16; ++j) {
          int f = (2 * mg + mm) * 32 + (j & 3) + 8 * (j >> 2) + 4 * lhalf;
          float sv = silu_f(acc0[mm][nn][j] + bias);
          xres[mm][nn][j] = sv;
          int xc = f & 15;
          if (f >= 16 && f < 255 && xc < 15)
            Ab[loff(f + 17, c)] = (_Float16)sv;
        }
      }
  }
  __syncthreads();

  floatx16 acc[2][2];
  const _Float16* wdc = ws + O_DC;
  const _Float16* wpx = ws + O_PX;

#pragma unroll 1
  for (int blk = 0; blk < 4; ++blk) {
    // dirconv: A -> silu -> B
    run_gemm<3, 2>(Ab, 17, sh0, sh2, wdc + blk * 3 * 16384, mg, ng, lrow, lk8, acc);
    {
      const float* bp = b_dc + blk * 128;
#pragma unroll
      for (int mm = 0; mm < 2; ++mm)
#pragma unroll
        for (int nn = 0; nn < 2; ++nn) {
          int c = (2 * ng + nn) * 32 + lrow;
          float bias = bp[c];
#pragma unroll
          for (int j = 0; j < 16; ++j) {
            int f = (2 * mg + mm) * 32 + (j & 3) + 8 * (j >> 2) + 4 * lhalf;
            Bb[loff(f, c)] = (_Float16)silu_f(acc[mm][nn][j] + bias);
          }
        }
    }
    __syncthreads();
    // 1x1: B -> silu -> residual add -> A (masked; pads stay 0)
    run_gemm<1, 2>(Bb, 0, 0, 0, wpx + blk * 16384, mg, ng, lrow, lk8, acc);
    {
      const float* bq = b_px + blk * 128;
#pragma unroll
      for (int mm = 0; mm < 2; ++mm)
#pragma unroll
        for (int nn = 0; nn < 2; ++nn) {
          int c = (2 * ng + nn) * 32 + lrow;
          float bias = bq[c];
#pragma unroll
          for (int j = 0; j < 16; ++j) {
            int f = (2 * mg + mm) * 32 + (j & 3) + 8 * (j >> 2) + 4 * lhalf;
            float t2 = silu_f(acc[mm][nn][j] + bias);
            float nv = xres[mm][nn][j] + t2;
            xres[mm][nn][j] = nv;
            int xc = f & 15;
            if (f >= 16 && f < 255 && xc < 15)
              Ab[loff(f + 17, c)] = (_Float16)nv;
          }
        }
    }
    __syncthreads();
  }

  // ---- Conv0dResBlock: c1 (A -> silu -> B), c2 (B -> silu -> +res -> A) ----
  run_gemm<1, 2>(Ab, 17, 0, 0, ws + O_C1, mg, ng, lrow, lk8, acc);
  {
#pragma unroll
    for (int mm = 0; mm < 2; ++mm)
#pragma unroll
      for (int nn = 0; nn < 2; ++nn) {
        int c = (2 * ng + nn) * 32 + lrow;
        float bias = b_c1[c];
#pragma unroll
        for (int j = 0; j < 16; ++j) {
          int f = (2 * mg + mm) * 32 + (j & 3) + 8 * (j >> 2) + 4 * lhalf;
          Bb[loff(f, c)] = (_Float16)silu_f(acc[mm][nn][j] + bias);
        }
      }
  }
  __syncthreads();
  run_gemm<1, 2>(Bb, 0, 0, 0, ws + O_C2, mg, ng, lrow, lk8, acc);
  {
#pragma unroll
    for (int mm = 0; mm < 2; ++mm)
#pragma unroll
      for (int nn = 0; nn < 2; ++nn) {
        int c = (2 * ng + nn) * 32 + lrow;
        float bias = b_c2[c];
#pragma unroll
        for (int j = 0; j < 16; ++j) {
          int f = (2 * mg + mm) * 32 + (j & 3) + 8 * (j >> 2) + 4 * lhalf;
          float t2 = silu_f(acc[mm][nn][j] + bias);
          float nv = xres[mm][nn][j] + t2;
          xres[mm][nn][j] = nv;
          int xc = f & 15;
          if (f >= 16 && f < 255 && xc < 15)
            Ab[loff(f + 17, c)] = (_Float16)nv;
        }
      }
  }
  __syncthreads();

  // ---- final 1x1 (N=64, no silu): A -> staging (transpose) -> coalesced out ----
  run_gemm<1, 1>(Ab, 17, 0, 0, ws + O_F, mg, ng, lrow, lk8, acc);
  float* stg = (float*)Bb;   // [64][225] fp32 = 57.6 KB
  {
    int c = ng * 32 + lrow;
    float bias = b_f[c];
#pragma unroll
    for (int mm = 0; mm < 2; ++mm)
#pragma unroll
      for (int j = 0; j < 16; ++j) {
        int f = (2 * mg + mm) * 32 + (j & 3) + 8 * (j >> 2) + 4 * lhalf;
        int y = (f >> 4) - 1, xx = f & 15;
        float v = acc[mm][0][j] + bias;
        if (y >= 0 && y < 15 && xx < 15)
          stg[c * 225 + y * 15 + xx] = v;
      }
  }
  __syncthreads();
  {
    size_t base = (size_t)bid * 14400;
    for (int i = tid; i < 14400; i += 512) out[base + i] = stg[i];
  }
}

extern "C" void kernel_launch(void* const* d_in, const int* in_sizes, int n_in,
                              void* d_out, int out_size, void* d_ws, size_t ws_size,
                              hipStream_t stream) {
  (void)in_sizes; (void)n_in; (void)out_size;
  const float* x    = (const float*)d_in[0];
  const float* w_d0 = (const float*)d_in[1];
  const float* b_d0 = (const float*)d_in[2];
  const float* w_dc = (const float*)d_in[3];
  const float* b_dc = (const float*)d_in[4];
  const float* w_px = (const float*)d_in[5];
  const float* b_px = (const float*)d_in[6];
  const float* w_c1 = (const float*)d_in[7];
  const float* b_c1 = (const float*)d_in[8];
  const float* w_c2 = (const float*)d_in[9];
  const float* b_c2 = (const float*)d_in[10];
  const float* w_f  = (const float*)d_in[11];
  const float* b_f  = (const float*)d_in[12];
  float* out = (float*)d_out;
  _Float16* ws = (_Float16*)d_ws;
  if (ws_size < (size_t)W_TOTAL * sizeof(_Float16)) return;  // fail loudly

  wconv_kernel<<<(W_TOTAL + 255) / 256, 256, 0, stream>>>(w_d0, w_dc, w_px, w_c1, w_c2, w_f, ws);
  mixnet_kernel<<<4096, 512, 0, stream>>>(x, ws, b_d0, b_dc, b_px, b_c1, b_c2, b_f, out);
}

// Round 2
// 2740.773 us; speedup vs baseline: 1.5390x; 1.5390x over previous
//
#include <hip/hip_runtime.h>

typedef _Float16 half8 __attribute__((ext_vector_type(8)));
typedef float floatx16 __attribute__((ext_vector_type(16)));

#define MFMA16(a,b,c) __builtin_amdgcn_mfma_f32_32x32x16_f16((a),(b),(c),0,0,0)

// fp16 weight workspace layout (element offsets)
#define O_D0 0
#define N_D0 768
#define O_DC (O_D0 + N_D0)      // 768
#define N_DC 196608
#define O_PX (O_DC + N_DC)      // 197376
#define N_PX 65536
#define O_C1 (O_PX + N_PX)      // 262912
#define O_C2 (O_C1 + 16384)     // 279296
#define O_F  (O_C2 + 16384)     // 295680
#define W_TOTAL (O_F + 8192)    // 303872 elements

// GEMM weight tensors are stored as [t][kk=k/16][c][k%16] so one wave's
// B-fragment load (32 consecutive c, 32B each) is a contiguous 1KB block.
__global__ void wconv_kernel(const float* __restrict__ w_d0, const float* __restrict__ w_dc,
                             const float* __restrict__ w_px, const float* __restrict__ w_c1,
                             const float* __restrict__ w_c2, const float* __restrict__ w_f,
                             _Float16* __restrict__ ws) {
  int i = blockIdx.x * 256 + threadIdx.x;
  if (i >= W_TOTAL) return;
  float v; int dst;
  if (i < O_DC) {                       // d0: identity layout [t][c][ci]
    v = w_d0[i]; dst = O_D0 + i;
  } else if (i < O_PX) {                // dc: [blk][t][c][k] -> [blk][t][kk][c][k16]
    int s = i - O_DC;
    int k = s & 127; int r = s >> 7; int c = r & 127; int bt = r >> 7;
    int t = bt % 3, blk = bt / 3;
    dst = O_DC + blk * 49152 + ((t * 8 + (k >> 4)) * 128 + c) * 16 + (k & 15);
    v = w_dc[s];
  } else if (i < O_C1) {                // px
    int s = i - O_PX;
    int k = s & 127; int r = s >> 7; int c = r & 127; int blk = r >> 7;
    dst = O_PX + blk * 16384 + ((k >> 4) * 128 + c) * 16 + (k & 15);
    v = w_px[s];
  } else if (i < O_C2) {                // c1
    int s = i - O_C1;
    int k = s & 127; int c = s >> 7;
    dst = O_C1 + ((k >> 4) * 128 + c) * 16 + (k & 15);
    v = w_c1[s];
  } else if (i < O_F) {                 // c2
    int s = i - O_C2;
    int k = s & 127; int c = s >> 7;
    dst = O_C2 + ((k >> 4) * 128 + c) * 16 + (k & 15);
    v = w_c2[s];
  } else {                              // f: 64 rows
    int s = i - O_F;
    int k = s & 127; int c = s >> 7;
    dst = O_F + ((k >> 4) * 64 + c) * 16 + (k & 15);
    v = w_f[s];
  }
  ws[dst] = (_Float16)v;
}

__device__ __forceinline__ float silu_f(float v) {
  return v / (1.0f + __expf(-v));
}

// swizzled LDS element offset for [pixel][128ch] fp16 tiles
__device__ __forceinline__ int loff(int p, int k) {
  return p * 128 + (k ^ ((p & 15) << 3));
}

__device__ __forceinline__ floatx16 zero16() {
  floatx16 z;
#pragma unroll
  for (int i = 0; i < 16; ++i) z[i] = 0.0f;
  return z;
}

// GEMM: out[f][c] = sum_t sum_k A[f + sh_t][k] * W[t][c][k]
// A from LDS (swizzled), weights fp16 from global in [t][kk][c][k16] layout.
// 8 waves: mg in 0..3 -> m-tiles {2mg,2mg+1} (32 px each), ng in 0..1 -> NT n-tiles.
template<int TAPS, int NT>
__device__ __forceinline__ void run_gemm(
    const _Float16* asrc, int abase, int sh0, int sh2,
    const _Float16* __restrict__ wq,
    int mg, int ng, int lrow, int lk8,
    floatx16 acc[2][2])
{
  const int NROWS = NT * 64;
  const int sh[3] = {sh0, 0, sh2};
  int pb[TAPS][2], psw[TAPS][2];
  const _Float16* wp[TAPS][NT];
#pragma unroll
  for (int t = 0; t < TAPS; ++t) {
#pragma unroll
    for (int mm = 0; mm < 2; ++mm) {
      int p = abase + (2 * mg + mm) * 32 + lrow + (TAPS == 3 ? sh[t] : 0);
      pb[t][mm] = p * 128;
      psw[t][mm] = (p & 15) << 3;
    }
#pragma unroll
    for (int nn = 0; nn < NT; ++nn) {
      int c = (NT == 2 ? (2 * ng + nn) : ng) * 32 + lrow;
      wp[t][nn] = wq + (t * 8 * NROWS + c) * 16 + lk8;
    }
  }
#pragma unroll
  for (int mm = 0; mm < 2; ++mm)
#pragma unroll
    for (int nn = 0; nn < NT; ++nn)
      acc[mm][nn] = zero16();

#pragma unroll
  for (int kk = 0; kk < 8; ++kk) {
    const int k = kk * 16 + lk8;
    half8 bf[TAPS][NT], af[TAPS][2];
#pragma unroll
    for (int t = 0; t < TAPS; ++t)
#pragma unroll
      for (int nn = 0; nn < NT; ++nn)
        bf[t][nn] = *(const half8*)(wp[t][nn] + kk * (NROWS * 16));
#pragma unroll
    for (int t = 0; t < TAPS; ++t)
#pragma unroll
      for (int mm = 0; mm < 2; ++mm)
        af[t][mm] = *(const half8*)&asrc[pb[t][mm] + (k ^ psw[t][mm])];
#pragma unroll
    for (int t = 0; t < TAPS; ++t)
#pragma unroll
      for (int mm = 0; mm < 2; ++mm)
#pragma unroll
        for (int nn = 0; nn < NT; ++nn)
          acc[mm][nn] = MFMA16(af[t][mm], bf[t][nn], acc[mm][nn]);
  }
}

__global__ __launch_bounds__(512, 2) void mixnet_kernel(
    const float* __restrict__ xin, const _Float16* __restrict__ ws,
    const float* __restrict__ b_d0, const float* __restrict__ b_dc,
    const float* __restrict__ b_px, const float* __restrict__ b_c1,
    const float* __restrict__ b_c2, const float* __restrict__ b_f,
    float* __restrict__ out)
{
  // A: padded activation buffer, pixel addr pa = f + 17, pa in [0,290)
  __shared__ _Float16 Ab[290 * 128];   // 74240 B
  __shared__ _Float16 Bb[256 * 128];   // 65536 B

  const int bid = blockIdx.x;
  const int b = bid >> 2, d = bid & 3;
  const int tid = threadIdx.x;
  const int wv = tid >> 6, l = tid & 63;
  const int mg = wv >> 1, ng = wv & 1;
  const int lrow = l & 31;
  const int lk8 = (l >> 5) << 3;
  const int lhalf = l >> 5;

  static const int DYT[4][3] = {{0,0,0},{-1,0,1},{-1,0,1},{1,0,-1}};
  static const int DXT[4][3] = {{-1,0,1},{0,0,0},{-1,0,1},{-1,0,1}};
  const int sh0 = DYT[d][0] * 16 + DXT[d][0];
  const int sh2 = DYT[d][2] * 16 + DXT[d][2];

  // ---- zero A buffer (pads must stay 0 forever) ----
  {
    int* Ai = (int*)Ab;
    for (int i = tid; i < 290 * 128 / 2; i += 512) Ai[i] = 0;
  }
  // ---- staging for initial conv in B region: Axt[256][16], wBs[128][16] ----
  _Float16* Axt = Bb;          // 4096 halves
  _Float16* wBs = Bb + 4096;   // 2048 halves
  {
    int* Bi = (int*)Bb;
    for (int i = tid; i < (4096 + 2048) / 2; i += 512) Bi[i] = 0;
  }
  __syncthreads();
  // gather shifted x into Axt: k = t*2 + ci, zero outside image (pow-2 strides, no int div)
  for (int i = tid; i < 256 * 8; i += 512) {
    int f = i >> 3, k = i & 7;
    if (k < 6) {
      int t = k >> 1, ci = k & 1;
      int y = (f >> 4) - 1 + DYT[d][t];
      int xx = (f & 15) + DXT[d][t];
      float v = 0.0f;
      if (y >= 0 && y < 15 && xx >= 0 && xx < 15)
        v = xin[b * 450 + ci * 225 + y * 15 + xx];
      Axt[f * 16 + k] = (_Float16)v;
    }
  }
  for (int i = tid; i < 128 * 8; i += 512) {
    int c = i >> 3, k = i & 7;
    if (k < 6) {
      int t = k >> 1, ci = k & 1;
      wBs[c * 16 + k] = ws[O_D0 + (t * 128 + c) * 2 + ci];
    }
  }
  __syncthreads();

  // ---- initial dirconv via one K=16 MFMA step ----
  {
    half8 af[2], bf[2];
#pragma unroll
    for (int mm = 0; mm < 2; ++mm) {
      int p = (2 * mg + mm) * 32 + lrow;
      af[mm] = *(const half8*)&Axt[p * 16 + lk8];
    }
#pragma unroll
    for (int nn = 0; nn < 2; ++nn) {
      int c = (2 * ng + nn) * 32 + lrow;
      bf[nn] = *(const half8*)&wBs[c * 16 + lk8];
    }
    floatx16 acc0[2][2];
#pragma unroll
    for (int mm = 0; mm < 2; ++mm)
#pragma unroll
      for (int nn = 0; nn < 2; ++nn) {
        acc0[mm][nn] = zero16();
        acc0[mm][nn] = MFMA16(af[mm], bf[nn], acc0[mm][nn]);
      }
    __syncthreads();  // done reading Axt/wBs from Bb region
#pragma unroll
    for (int mm = 0; mm < 2; ++mm)
#pragma unroll
      for (int nn = 0; nn < 2; ++nn) {
        int c = (2 * ng + nn) * 32 + lrow;
        float bias = b_d0[c];
#pragma unroll
        for (int j = 0; j < 16; ++j) {
          int f = (2 * mg + mm) * 32 + (j & 3) + 8 * (j >> 2) + 4 * lhalf;
          float sv = silu_f(acc0[mm][nn][j] + bias);
          int xc = f & 15;
          if (f >= 16 && f < 255 && xc < 15)
            Ab[loff(f + 17, c)] = (_Float16)sv;
        }
      }
  }
  __syncthreads();

  floatx16 acc[2][2];
  const _Float16* wdc = ws + O_DC;
  const _Float16* wpx = ws + O_PX;

#pragma unroll 1
  for (int blk = 0; blk < 4; ++blk) {
    // dirconv: A -> silu -> B
    run_gemm<3, 2>(Ab, 17, sh0, sh2, wdc + blk * 49152, mg, ng, lrow, lk8, acc);
    {
      const float* bp = b_dc + blk * 128;
#pragma unroll
      for (int mm = 0; mm < 2; ++mm)
#pragma unroll
        for (int nn = 0; nn < 2; ++nn) {
          int c = (2 * ng + nn) * 32 + lrow;
          float bias = bp[c];
#pragma unroll
          for (int j = 0; j < 16; ++j) {
            int f = (2 * mg + mm) * 32 + (j & 3) + 8 * (j >> 2) + 4 * lhalf;
            Bb[loff(f, c)] = (_Float16)silu_f(acc[mm][nn][j] + bias);
          }
        }
    }
    __syncthreads();
    // 1x1: B -> silu -> residual add (residual read back from Ab, fp16) -> A
    run_gemm<1, 2>(Bb, 0, 0, 0, wpx + blk * 16384, mg, ng, lrow, lk8, acc);
    {
      const float* bq = b_px + blk * 128;
#pragma unroll
      for (int mm = 0; mm < 2; ++mm)
#pragma unroll
        for (int nn = 0; nn < 2; ++nn) {
          int c = (2 * ng + nn) * 32 + lrow;
          float bias = bq[c];
#pragma unroll
          for (int j = 0; j < 16; ++j) {
            int f = (2 * mg + mm) * 32 + (j & 3) + 8 * (j >> 2) + 4 * lhalf;
            float t2 = silu_f(acc[mm][nn][j] + bias);
            float resv = (float)Ab[loff(f + 17, c)];
            float nv = resv + t2;
            int xc = f & 15;
            if (f >= 16 && f < 255 && xc < 15)
              Ab[loff(f + 17, c)] = (_Float16)nv;
          }
        }
    }
    __syncthreads();
  }

  // ---- Conv0dResBlock: c1 (A -> silu -> B), c2 (B -> silu -> +res -> A) ----
  run_gemm<1, 2>(Ab, 17, 0, 0, ws + O_C1, mg, ng, lrow, lk8, acc);
  {
#pragma unroll
    for (int mm = 0; mm < 2; ++mm)
#pragma unroll
      for (int nn = 0; nn < 2; ++nn) {
        int c = (2 * ng + nn) * 32 + lrow;
        float bias = b_c1[c];
#pragma unroll
        for (int j = 0; j < 16; ++j) {
          int f = (2 * mg + mm) * 32 + (j & 3) + 8 * (j >> 2) + 4 * lhalf;
          Bb[loff(f, c)] = (_Float16)silu_f(acc[mm][nn][j] + bias);
        }
      }
  }
  __syncthreads();
  run_gemm<1, 2>(Bb, 0, 0, 0, ws + O_C2, mg, ng, lrow, lk8, acc);
  {
#pragma unroll
    for (int mm = 0; mm < 2; ++mm)
#pragma unroll
      for (int nn = 0; nn < 2; ++nn) {
        int c = (2 * ng + nn) * 32 + lrow;
        float bias = b_c2[c];
#pragma unroll
        for (int j = 0; j < 16; ++j) {
          int f = (2 * mg + mm) * 32 + (j & 3) + 8 * (j >> 2) + 4 * lhalf;
          float t2 = silu_f(acc[mm][nn][j] + bias);
          float resv = (float)Ab[loff(f + 17, c)];
          float nv = resv + t2;
          int xc = f & 15;
          if (f >= 16 && f < 255 && xc < 15)
            Ab[loff(f + 17, c)] = (_Float16)nv;
        }
      }
  }
  __syncthreads();

  // ---- final 1x1 (N=64, no silu): A -> staging (transpose) -> coalesced out ----
  run_gemm<1, 1>(Ab, 17, 0, 0, ws + O_F, mg, ng, lrow, lk8, acc);
  float* stg = (float*)Bb;   // [64][225] fp32 = 57.6 KB
  {
    int c = ng * 32 + lrow;
    float bias = b_f[c];
#pragma unroll
    for (int mm = 0; mm < 2; ++mm)
#pragma unroll
      for (int j = 0; j < 16; ++j) {
        int f = (2 * mg + mm) * 32 + (j & 3) + 8 * (j >> 2) + 4 * lhalf;
        int y = (f >> 4) - 1, xx = f & 15;
        float v = acc[mm][0][j] + bias;
        if (y >= 0 && y < 15 && xx < 15)
          stg[c * 225 + y * 15 + xx] = v;
      }
  }
  __syncthreads();
  {
    size_t base = (size_t)bid * 14400;
    for (int i = tid; i < 14400; i += 512) out[base + i] = stg[i];
  }
}

extern "C" void kernel_launch(void* const* d_in, const int* in_sizes, int n_in,
                              void* d_out, int out_size, void* d_ws, size_t ws_size,
                              hipStream_t stream) {
  (void)in_sizes; (void)n_in; (void)out_size;
  const float* x    = (const float*)d_in[0];
  const float* w_d0 = (const float*)d_in[1];
  const float* b_d0 = (const float*)d_in[2];
  const float* w_dc = (const float*)d_in[3];
  const float* b_dc = (const float*)d_in[4];
  const float* w_px = (const float*)d_in[5];
  const float* b_px = (const float*)d_in[6];
  const float* w_c1 = (const float*)d_in[7];
  const float* b_c1 = (const float*)d_in[8];
  const float* w_c2 = (const float*)d_in[9];
  const float* b_c2 = (const float*)d_in[10];
  const float* w_f  = (const float*)d_in[11];
  const float* b_f  = (const float*)d_in[12];
  float* out = (float*)d_out;
  _Float16* ws = (_Float16*)d_ws;
  if (ws_size < (size_t)W_TOTAL * sizeof(_Float16)) return;  // fail loudly

  wconv_kernel<<<(W_TOTAL + 255) / 256, 256, 0, stream>>>(w_d0, w_dc, w_px, w_c1, w_c2, w_f, ws);
  mixnet_kernel<<<4096, 512, 0, stream>>>(x, ws, b_d0, b_dc, b_px, b_c1, b_c2, b_f, out);
}

// Round 3
// 1744.905 us; speedup vs baseline: 2.4174x; 1.5707x over previous
//
#include <hip/hip_runtime.h>

typedef _Float16 half8 __attribute__((ext_vector_type(8)));
typedef float floatx16 __attribute__((ext_vector_type(16)));

#define MFMA16(a,b,c) __builtin_amdgcn_mfma_f32_32x32x16_f16((a),(b),(c),0,0,0)

// fp16 weight workspace layout (element offsets)
#define O_D0 0
#define N_D0 768
#define O_DC (O_D0 + N_D0)      // 768
#define N_DC 196608
#define O_PX (O_DC + N_DC)      // 197376
#define N_PX 65536
#define O_C1 (O_PX + N_PX)      // 262912
#define O_C2 (O_C1 + 16384)     // 279296
#define O_F  (O_C2 + 16384)     // 295680
#define W_TOTAL (O_F + 8192)    // 303872 elements

// GEMM weight tensors are stored as [t][kk=k/16][c][k%16] so one wave's
// B-fragment load (32 consecutive c, 32B each) is a contiguous 1KB block.
__global__ void wconv_kernel(const float* __restrict__ w_d0, const float* __restrict__ w_dc,
                             const float* __restrict__ w_px, const float* __restrict__ w_c1,
                             const float* __restrict__ w_c2, const float* __restrict__ w_f,
                             _Float16* __restrict__ ws) {
  int i = blockIdx.x * 256 + threadIdx.x;
  if (i >= W_TOTAL) return;
  float v; int dst;
  if (i < O_DC) {                       // d0: identity layout [t][c][ci]
    v = w_d0[i]; dst = O_D0 + i;
  } else if (i < O_PX) {                // dc: [blk][t][c][k] -> [blk][t][kk][c][k16]
    int s = i - O_DC;
    int k = s & 127; int r = s >> 7; int c = r & 127; int bt = r >> 7;
    int t = bt % 3, blk = bt / 3;
    dst = O_DC + blk * 49152 + ((t * 8 + (k >> 4)) * 128 + c) * 16 + (k & 15);
    v = w_dc[s];
  } else if (i < O_C1) {                // px
    int s = i - O_PX;
    int k = s & 127; int r = s >> 7; int c = r & 127; int blk = r >> 7;
    dst = O_PX + blk * 16384 + ((k >> 4) * 128 + c) * 16 + (k & 15);
    v = w_px[s];
  } else if (i < O_C2) {                // c1
    int s = i - O_C1;
    int k = s & 127; int c = s >> 7;
    dst = O_C1 + ((k >> 4) * 128 + c) * 16 + (k & 15);
    v = w_c1[s];
  } else if (i < O_F) {                 // c2
    int s = i - O_C2;
    int k = s & 127; int c = s >> 7;
    dst = O_C2 + ((k >> 4) * 128 + c) * 16 + (k & 15);
    v = w_c2[s];
  } else {                              // f: 64 rows
    int s = i - O_F;
    int k = s & 127; int c = s >> 7;
    dst = O_F + ((k >> 4) * 64 + c) * 16 + (k & 15);
    v = w_f[s];
  }
  ws[dst] = (_Float16)v;
}

__device__ __forceinline__ float silu_f(float v) {
  // v * rcp(1+exp(-v)) : ~1ulp rcp, fine for fp16-rounded storage
  float e = __expf(-v);
  return v * __builtin_amdgcn_rcpf(1.0f + e);
}

// swizzled LDS element offset for [pixel][128ch] fp16 tiles
__device__ __forceinline__ int loff(int p, int k) {
  return p * 128 + (k ^ ((p & 15) << 3));
}

__device__ __forceinline__ void zeroacc(floatx16 acc[2][2]) {
#pragma unroll
  for (int mm = 0; mm < 2; ++mm)
#pragma unroll
    for (int nn = 0; nn < 2; ++nn)
#pragma unroll
      for (int i = 0; i < 16; ++i) acc[mm][nn][i] = 0.0f;
}

// One accumulation pass: acc[mm][nn] += A[row0 + mm*32 .. +31][k] * W[c][k]
// A from swizzled LDS; W fp16 from global, layout [kk][c][k16] (c rows of 32B).
// row0 is this lane's pixel row for mm=0 (includes lrow and any tap shift).
template<int NT>
__device__ __forceinline__ void gemm_pass(
    const _Float16* asrc, int row0,
    const _Float16* __restrict__ wq,
    int boff, int lk8, floatx16 acc[2][2])
{
  const int KSTRIDE = NT * 64 * 16;  // elements per kk step
  const int pb0 = row0 * 128;
  const int psw = (row0 & 15) << 3;  // same for row0+32
#pragma unroll
  for (int kk = 0; kk < 8; ++kk) {
    const int kx = (kk * 16 + lk8) ^ psw;
    half8 a0 = *(const half8*)&asrc[pb0 + kx];
    half8 a1 = *(const half8*)&asrc[pb0 + 4096 + kx];
    half8 b0 = *(const half8*)&wq[kk * KSTRIDE + boff];
    half8 b1;
    if (NT == 2) b1 = *(const half8*)&wq[kk * KSTRIDE + boff + 512];
    acc[0][0] = MFMA16(a0, b0, acc[0][0]);
    acc[1][0] = MFMA16(a1, b0, acc[1][0]);
    if (NT == 2) {
      acc[0][1] = MFMA16(a0, b1, acc[0][1]);
      acc[1][1] = MFMA16(a1, b1, acc[1][1]);
    }
  }
}

__global__ __launch_bounds__(512, 2) void mixnet_kernel(
    const float* __restrict__ xin, const _Float16* __restrict__ ws,
    const float* __restrict__ b_d0, const float* __restrict__ b_dc,
    const float* __restrict__ b_px, const float* __restrict__ b_c1,
    const float* __restrict__ b_c2, const float* __restrict__ b_f,
    float* __restrict__ out)
{
  // A: padded activation buffer, pixel addr pa = f + 17, pa in [0,290)
  __shared__ _Float16 Ab[290 * 128];   // 74240 B
  __shared__ _Float16 Bb[256 * 128];   // 65536 B

  const int bid = blockIdx.x;
  const int b = bid >> 2, d = bid & 3;
  const int tid = threadIdx.x;
  const int wv = tid >> 6, l = tid & 63;
  const int mg = wv >> 1, ng = wv & 1;
  const int lrow = l & 31;
  const int lk8 = (l >> 5) << 3;
  const int lhalf = l >> 5;

  static const int DYT[4][3] = {{0,0,0},{-1,0,1},{-1,0,1},{1,0,-1}};
  static const int DXT[4][3] = {{-1,0,1},{0,0,0},{-1,0,1},{-1,0,1}};
  const int sh0 = DYT[d][0] * 16 + DXT[d][0];
  const int sh2 = DYT[d][2] * 16 + DXT[d][2];

  // per-lane constants for GEMMs
  const int arow = 2 * mg * 32 + lrow;                 // A pixel row, mm=0 (no pad)
  const int boff2 = (2 * ng * 32 + lrow) * 16 + lk8;   // NT=2 weight lane offset
  const int boff1 = (ng * 32 + lrow) * 16 + lk8;       // NT=1 (final)

  // ---- zero A buffer (pads must stay 0 forever) ----
  {
    int* Ai = (int*)Ab;
    for (int i = tid; i < 290 * 128 / 2; i += 512) Ai[i] = 0;
  }
  // ---- staging for initial conv in B region: Axt[256][16], wBs[128][16] ----
  _Float16* Axt = Bb;          // 4096 halves
  _Float16* wBs = Bb + 4096;   // 2048 halves
  {
    int* Bi = (int*)Bb;
    for (int i = tid; i < (4096 + 2048) / 2; i += 512) Bi[i] = 0;
  }
  __syncthreads();
  // gather shifted x into Axt: k = t*2 + ci, zero outside image
  for (int i = tid; i < 256 * 8; i += 512) {
    int f = i >> 3, k = i & 7;
    if (k < 6) {
      int t = k >> 1, ci = k & 1;
      int y = (f >> 4) - 1 + DYT[d][t];
      int xx = (f & 15) + DXT[d][t];
      float v = 0.0f;
      if (y >= 0 && y < 15 && xx >= 0 && xx < 15)
        v = xin[b * 450 + ci * 225 + y * 15 + xx];
      Axt[f * 16 + k] = (_Float16)v;
    }
  }
  for (int i = tid; i < 128 * 8; i += 512) {
    int c = i >> 3, k = i & 7;
    if (k < 6) {
      int t = k >> 1, ci = k & 1;
      wBs[c * 16 + k] = ws[O_D0 + (t * 128 + c) * 2 + ci];
    }
  }
  __syncthreads();

  // ---- initial dirconv via one K=16 MFMA step ----
  {
    half8 af[2], bf[2];
#pragma unroll
    for (int mm = 0; mm < 2; ++mm)
      af[mm] = *(const half8*)&Axt[(arow + mm * 32) * 16 + lk8];
#pragma unroll
    for (int nn = 0; nn < 2; ++nn)
      bf[nn] = *(const half8*)&wBs[((2 * ng + nn) * 32 + lrow) * 16 + lk8];
    floatx16 acc0[2][2];
    zeroacc(acc0);
#pragma unroll
    for (int mm = 0; mm < 2; ++mm)
#pragma unroll
      for (int nn = 0; nn < 2; ++nn)
        acc0[mm][nn] = MFMA16(af[mm], bf[nn], acc0[mm][nn]);
    __syncthreads();  // done reading Axt/wBs from Bb region
#pragma unroll
    for (int mm = 0; mm < 2; ++mm)
#pragma unroll
      for (int nn = 0; nn < 2; ++nn) {
        int c = (2 * ng + nn) * 32 + lrow;
        float bias = b_d0[c];
#pragma unroll
        for (int j = 0; j < 16; ++j) {
          int f = (2 * mg + mm) * 32 + (j & 3) + 8 * (j >> 2) + 4 * lhalf;
          float sv = silu_f(acc0[mm][nn][j] + bias);
          int xc = f & 15;
          if (f >= 16 && f < 255 && xc < 15)
            Ab[loff(f + 17, c)] = (_Float16)sv;
        }
      }
  }
  __syncthreads();

  floatx16 acc[2][2];
  const _Float16* wdc = ws + O_DC;
  const _Float16* wpx = ws + O_PX;

#pragma unroll 1
  for (int blk = 0; blk < 4; ++blk) {
    // dirconv: A -> silu -> B ; three accumulation passes (taps outermost)
    {
      const _Float16* wt = wdc + blk * 49152;
      zeroacc(acc);
      gemm_pass<2>(Ab, 17 + arow + sh0, wt,          boff2, lk8, acc);
      gemm_pass<2>(Ab, 17 + arow,       wt + 16384,  boff2, lk8, acc);
      gemm_pass<2>(Ab, 17 + arow + sh2, wt + 32768,  boff2, lk8, acc);
      const float* bp = b_dc + blk * 128;
#pragma unroll
      for (int mm = 0; mm < 2; ++mm)
#pragma unroll
        for (int nn = 0; nn < 2; ++nn) {
          int c = (2 * ng + nn) * 32 + lrow;
          float bias = bp[c];
#pragma unroll
          for (int j = 0; j < 16; ++j) {
            int f = (2 * mg + mm) * 32 + (j & 3) + 8 * (j >> 2) + 4 * lhalf;
            Bb[loff(f, c)] = (_Float16)silu_f(acc[mm][nn][j] + bias);
          }
        }
    }
    __syncthreads();
    // 1x1: B -> silu -> residual add (residual read back from Ab, fp16) -> A
    {
      zeroacc(acc);
      gemm_pass<2>(Bb, arow, wpx + blk * 16384, boff2, lk8, acc);
      const float* bq = b_px + blk * 128;
#pragma unroll
      for (int mm = 0; mm < 2; ++mm)
#pragma unroll
        for (int nn = 0; nn < 2; ++nn) {
          int c = (2 * ng + nn) * 32 + lrow;
          float bias = bq[c];
#pragma unroll
          for (int j = 0; j < 16; ++j) {
            int f = (2 * mg + mm) * 32 + (j & 3) + 8 * (j >> 2) + 4 * lhalf;
            float t2 = silu_f(acc[mm][nn][j] + bias);
            float nv = (float)Ab[loff(f + 17, c)] + t2;
            int xc = f & 15;
            if (f >= 16 && f < 255 && xc < 15)
              Ab[loff(f + 17, c)] = (_Float16)nv;
          }
        }
    }
    __syncthreads();
  }

  // ---- Conv0dResBlock: c1 (A -> silu -> B), c2 (B -> silu -> +res -> A) ----
  {
    zeroacc(acc);
    gemm_pass<2>(Ab, 17 + arow, ws + O_C1, boff2, lk8, acc);
#pragma unroll
    for (int mm = 0; mm < 2; ++mm)
#pragma unroll
      for (int nn = 0; nn < 2; ++nn) {
        int c = (2 * ng + nn) * 32 + lrow;
        float bias = b_c1[c];
#pragma unroll
        for (int j = 0; j < 16; ++j) {
          int f = (2 * mg + mm) * 32 + (j & 3) + 8 * (j >> 2) + 4 * lhalf;
          Bb[loff(f, c)] = (_Float16)silu_f(acc[mm][nn][j] + bias);
        }
      }
  }
  __syncthreads();
  {
    zeroacc(acc);
    gemm_pass<2>(Bb, arow, ws + O_C2, boff2, lk8, acc);
#pragma unroll
    for (int mm = 0; mm < 2; ++mm)
#pragma unroll
      for (int nn = 0; nn < 2; ++nn) {
        int c = (2 * ng + nn) * 32 + lrow;
        float bias = b_c2[c];
#pragma unroll
        for (int j = 0; j < 16; ++j) {
          int f = (2 * mg + mm) * 32 + (j & 3) + 8 * (j >> 2) + 4 * lhalf;
          float t2 = silu_f(acc[mm][nn][j] + bias);
          float nv = (float)Ab[loff(f + 17, c)] + t2;
          int xc = f & 15;
          if (f >= 16 && f < 255 && xc < 15)
            Ab[loff(f + 17, c)] = (_Float16)nv;
        }
      }
  }
  __syncthreads();

  // ---- final 1x1 (N=64, no silu): A -> staging (transpose) -> coalesced out ----
  {
    zeroacc(acc);
    gemm_pass<1>(Ab, 17 + arow, ws + O_F, boff1, lk8, acc);
  }
  float* stg = (float*)Bb;   // [64][225] fp32 = 57.6 KB
  {
    int c = ng * 32 + lrow;
    float bias = b_f[c];
#pragma unroll
    for (int mm = 0; mm < 2; ++mm)
#pragma unroll
      for (int j = 0; j < 16; ++j) {
        int f = (2 * mg + mm) * 32 + (j & 3) + 8 * (j >> 2) + 4 * lhalf;
        int y = (f >> 4) - 1, xx = f & 15;
        float v = acc[mm][0][j] + bias;
        if (y >= 0 && y < 15 && xx < 15)
          stg[c * 225 + y * 15 + xx] = v;
      }
  }
  __syncthreads();
  {
    size_t base = (size_t)bid * 14400;
    for (int i = tid; i < 14400; i += 512)
      __builtin_nontemporal_store(stg[i], &out[base + i]);
  }
}

extern "C" void kernel_launch(void* const* d_in, const int* in_sizes, int n_in,
                              void* d_out, int out_size, void* d_ws, size_t ws_size,
                              hipStream_t stream) {
  (void)in_sizes; (void)n_in; (void)out_size;
  const float* x    = (const float*)d_in[0];
  const float* w_d0 = (const float*)d_in[1];
  const float* b_d0 = (const float*)d_in[2];
  const float* w_dc = (const float*)d_in[3];
  const float* b_dc = (const float*)d_in[4];
  const float* w_px = (const float*)d_in[5];
  const float* b_px = (const float*)d_in[6];
  const float* w_c1 = (const float*)d_in[7];
  const float* b_c1 = (const float*)d_in[8];
  const float* w_c2 = (const float*)d_in[9];
  const float* b_c2 = (const float*)d_in[10];
  const float* w_f  = (const float*)d_in[11];
  const float* b_f  = (const float*)d_in[12];
  float* out = (float*)d_out;
  _Float16* ws = (_Float16*)d_ws;
  if (ws_size < (size_t)W_TOTAL * sizeof(_Float16)) return;  // fail loudly

  wconv_kernel<<<(W_TOTAL + 255) / 256, 256, 0, stream>>>(w_d0, w_dc, w_px, w_c1, w_c2, w_f, ws);
  mixnet_kernel<<<4096, 512, 0, stream>>>(x, ws, b_d0, b_dc, b_px, b_c1, b_c2, b_f, out);
}

// Round 4
// 915.505 us; speedup vs baseline: 4.6075x; 1.9059x over previous
//
#include <hip/hip_runtime.h>

typedef _Float16 half8 __attribute__((ext_vector_type(8)));
typedef _Float16 half4v __attribute__((ext_vector_type(4)));
typedef float float4v __attribute__((ext_vector_type(4)));
typedef float floatx16 __attribute__((ext_vector_type(16)));

#define MFMA16(a,b,c) __builtin_amdgcn_mfma_f32_32x32x16_f16((a),(b),(c),0,0,0)

// fp16 weight workspace layout (element offsets)
#define O_D0 0
#define N_D0 768
#define O_DC (O_D0 + N_D0)      // 768
#define N_DC 196608
#define O_PX (O_DC + N_DC)      // 197376
#define N_PX 65536
#define O_C1 (O_PX + N_PX)      // 262912
#define O_C2 (O_C1 + 16384)     // 279296
#define O_F  (O_C2 + 16384)     // 295680
#define W_TOTAL (O_F + 8192)    // 303872 elements

// GEMM weight tensors stored as [kk=k/16][c][k%16]: one wave's fragment
// (32 consecutive c rows, 32B each) is a contiguous 1KB block.
__global__ void wconv_kernel(const float* __restrict__ w_d0, const float* __restrict__ w_dc,
                             const float* __restrict__ w_px, const float* __restrict__ w_c1,
                             const float* __restrict__ w_c2, const float* __restrict__ w_f,
                             _Float16* __restrict__ ws) {
  int i = blockIdx.x * 256 + threadIdx.x;
  if (i >= W_TOTAL) return;
  float v; int dst;
  if (i < O_DC) {                       // d0: identity layout [t][c][ci]
    v = w_d0[i]; dst = O_D0 + i;
  } else if (i < O_PX) {                // dc: [blk][t][c][k] -> [blk][t][kk][c][k16]
    int s = i - O_DC;
    int k = s & 127; int r = s >> 7; int c = r & 127; int bt = r >> 7;
    int t = bt % 3, blk = bt / 3;
    dst = O_DC + blk * 49152 + ((t * 8 + (k >> 4)) * 128 + c) * 16 + (k & 15);
    v = w_dc[s];
  } else if (i < O_C1) {                // px
    int s = i - O_PX;
    int k = s & 127; int r = s >> 7; int c = r & 127; int blk = r >> 7;
    dst = O_PX + blk * 16384 + ((k >> 4) * 128 + c) * 16 + (k & 15);
    v = w_px[s];
  } else if (i < O_C2) {                // c1
    int s = i - O_C1;
    int k = s & 127; int c = s >> 7;
    dst = O_C1 + ((k >> 4) * 128 + c) * 16 + (k & 15);
    v = w_c1[s];
  } else if (i < O_F) {                 // c2
    int s = i - O_C2;
    int k = s & 127; int c = s >> 7;
    dst = O_C2 + ((k >> 4) * 128 + c) * 16 + (k & 15);
    v = w_c2[s];
  } else {                              // f: 64 rows
    int s = i - O_F;
    int k = s & 127; int c = s >> 7;
    dst = O_F + ((k >> 4) * 64 + c) * 16 + (k & 15);
    v = w_f[s];
  }
  ws[dst] = (_Float16)v;
}

__device__ __forceinline__ float silu_f(float v) {
  float e = __expf(-v);
  return v * __builtin_amdgcn_rcpf(1.0f + e);
}

__device__ __forceinline__ int loff(int p, int k) {
  return p * 128 + (k ^ ((p & 15) << 3));
}

// acc init = per-channel bias (broadcast ds_read_b128 x4)
__device__ __forceinline__ floatx16 bias_init(const float* biasL, int slot, int cbase) {
  floatx16 a;
  const float* bp = biasL + slot * 128 + cbase;
#pragma unroll
  for (int g = 0; g < 4; ++g) {
    float4v v = *(const float4v*)(bp + 8 * g);
    a[4*g+0] = v[0]; a[4*g+1] = v[1]; a[4*g+2] = v[2]; a[4*g+3] = v[3];
  }
  return a;
}

// One accumulation pass (operands SWAPPED: weights are the A/row operand,
// activations the B/col operand -> output lanes = pixels, regs = channels).
// acc[mm] covers pixel rows row0 + mm*32.
template<int KSTRIDE>
__device__ __forceinline__ void gemm_pass(
    const _Float16* asrc, int row0,
    const _Float16* __restrict__ wq,
    int boff, int lk8, floatx16 acc[2])
{
  const int pb0 = row0 * 128;
  const int psw = (row0 & 15) << 3;  // same for row0+32
#pragma unroll
  for (int kk = 0; kk < 8; ++kk) {
    const int kx = (kk * 16 + lk8) ^ psw;
    half8 a0 = *(const half8*)&asrc[pb0 + kx];
    half8 a1 = *(const half8*)&asrc[pb0 + 4096 + kx];
    half8 w  = *(const half8*)&wq[kk * KSTRIDE + boff];
    acc[0] = MFMA16(w, a0, acc[0]);
    acc[1] = MFMA16(w, a1, acc[1]);
  }
}

// silu + fp16 store of 16 channels for pixel row p (unmasked, to Bb)
__device__ __forceinline__ void store_silu(_Float16* dst, int p, int cbase, const floatx16& a) {
  const int base = p * 128, s = (p & 15) << 3;
#pragma unroll
  for (int g = 0; g < 4; ++g) {
    half4v h;
#pragma unroll
    for (int j = 0; j < 4; ++j) h[j] = (_Float16)silu_f(a[4*g+j]);
    *(half4v*)&dst[base + ((cbase + 8*g) ^ s)] = h;
  }
}

// silu + masked store to Ab at padded row pa (initial conv)
__device__ __forceinline__ void store_silu_masked(_Float16* Abp, int pa, int cbase,
                                                  const floatx16& a, bool valid) {
  if (!valid) return;
  const int base = pa * 128, s = (pa & 15) << 3;
#pragma unroll
  for (int g = 0; g < 4; ++g) {
    half4v h;
#pragma unroll
    for (int j = 0; j < 4; ++j) h[j] = (_Float16)silu_f(a[4*g+j]);
    *(half4v*)&Abp[base + ((cbase + 8*g) ^ s)] = h;
  }
}

// residual: Ab[pa] += silu(acc), masked
__device__ __forceinline__ void resid_update(_Float16* Abp, int pa, int cbase,
                                             const floatx16& a, bool valid) {
  if (!valid) return;
  const int base = pa * 128, s = (pa & 15) << 3;
#pragma unroll
  for (int g = 0; g < 4; ++g) {
    int off = base + ((cbase + 8*g) ^ s);
    half4v r = *(const half4v*)&Abp[off];
    half4v h;
#pragma unroll
    for (int j = 0; j < 4; ++j) h[j] = (_Float16)((float)r[j] + silu_f(a[4*g+j]));
    *(half4v*)&Abp[off] = h;
  }
}

__global__ __launch_bounds__(1024, 1) void mixnet_kernel(
    const float* __restrict__ xin, const _Float16* __restrict__ ws,
    const float* __restrict__ b_d0, const float* __restrict__ b_dc,
    const float* __restrict__ b_px, const float* __restrict__ b_c1,
    const float* __restrict__ b_c2, const float* __restrict__ b_f,
    float* __restrict__ out)
{
  __shared__ _Float16 Ab[290 * 128];   // 74240 B, padded rows pa = f + 17
  __shared__ _Float16 Bb[256 * 128];   // 65536 B
  __shared__ float biasL[12 * 128];    // 6144 B: d0, dc0-3, px0-3, c1, c2, f

  const int bid = blockIdx.x;
  const int b = bid >> 2, d = bid & 3;
  const int tid = threadIdx.x;
  const int wv = tid >> 6, l = tid & 63;
  const int mg = wv >> 2, ng = wv & 3;         // 4 m-groups x 4 n-groups
  const int lrow = l & 31;
  const int lk8 = (l >> 5) << 3;
  const int lhalf = l >> 5;

  static const int DYT[4][3] = {{0,0,0},{-1,0,1},{-1,0,1},{1,0,-1}};
  static const int DXT[4][3] = {{-1,0,1},{0,0,0},{-1,0,1},{-1,0,1}};
  const int sh0 = DYT[d][0] * 16 + DXT[d][0];
  const int sh2 = DYT[d][2] * 16 + DXT[d][2];

  const int p0 = mg * 64 + lrow;                   // this lane's pixel row (mm=0)
  const int boff = (ng * 32 + lrow) * 16 + lk8;    // weight fragment lane offset
  const int cbase = ng * 32 + 4 * lhalf;           // channel base for acc regs
  const bool v0 = (p0 >= 16) && (p0 < 255) && ((p0 & 15) < 15);
  const int p1 = p0 + 32;
  const bool v1 = (p1 >= 16) && (p1 < 255) && ((p1 & 15) < 15);

  // ---- zero A buffer (pads must stay 0 forever) ----
  {
    int* Ai = (int*)Ab;
    for (int i = tid; i < 290 * 128 / 2; i += 1024) Ai[i] = 0;
  }
  // ---- stage biases ----
  for (int i = tid; i < 12 * 128; i += 1024) {
    int slot = i >> 7, c = i & 127; float v;
    if (slot == 0)       v = b_d0[c];
    else if (slot < 5)   v = b_dc[(slot - 1) * 128 + c];
    else if (slot < 9)   v = b_px[(slot - 5) * 128 + c];
    else if (slot == 9)  v = b_c1[c];
    else if (slot == 10) v = b_c2[c];
    else                 v = (c < 64) ? b_f[c] : 0.0f;
    biasL[i] = v;
  }
  // ---- staging for initial conv in B region: Axt[256][16], wBs[128][16] ----
  _Float16* Axt = Bb;          // 4096 halves
  _Float16* wBs = Bb + 4096;   // 2048 halves
  {
    int* Bi = (int*)Bb;
    for (int i = tid; i < (4096 + 2048) / 2; i += 1024) Bi[i] = 0;
  }
  __syncthreads();
  for (int i = tid; i < 256 * 8; i += 1024) {
    int f = i >> 3, k = i & 7;
    if (k < 6) {
      int t = k >> 1, ci = k & 1;
      int y = (f >> 4) - 1 + DYT[d][t];
      int xx = (f & 15) + DXT[d][t];
      float v = 0.0f;
      if (y >= 0 && y < 15 && xx >= 0 && xx < 15)
        v = xin[b * 450 + ci * 225 + y * 15 + xx];
      Axt[f * 16 + k] = (_Float16)v;
    }
  }
  for (int i = tid; i < 128 * 8; i += 1024) {
    int c = i >> 3, k = i & 7;
    if (k < 6) {
      int t = k >> 1, ci = k & 1;
      wBs[c * 16 + k] = ws[O_D0 + (t * 128 + c) * 2 + ci];
    }
  }
  __syncthreads();

  // ---- initial dirconv: one K=16 MFMA per pixel sub-tile ----
  {
    half8 a0 = *(const half8*)&Axt[p0 * 16 + lk8];
    half8 a1 = *(const half8*)&Axt[p1 * 16 + lk8];
    half8 w  = *(const half8*)&wBs[(ng * 32 + lrow) * 16 + lk8];
    floatx16 acc0 = bias_init(biasL, 0, cbase);
    floatx16 acc1 = acc0;
    acc0 = MFMA16(w, a0, acc0);
    acc1 = MFMA16(w, a1, acc1);
    __syncthreads();   // everyone done reading Axt/wBs before Ab write races? (Ab only; keep for epilogue/Bb reuse ordering)
    store_silu_masked(Ab, p0 + 17, cbase, acc0, v0);
    store_silu_masked(Ab, p1 + 17, cbase, acc1, v1);
  }
  __syncthreads();

  floatx16 acc[2];
  const _Float16* wdc = ws + O_DC;
  const _Float16* wpx = ws + O_PX;

#pragma unroll 1
  for (int blk = 0; blk < 4; ++blk) {
    // dirconv: A -> silu -> B ; three accumulation passes (taps outermost)
    {
      const _Float16* wt = wdc + blk * 49152;
      acc[0] = bias_init(biasL, 1 + blk, cbase);
      acc[1] = acc[0];
      gemm_pass<2048>(Ab, 17 + p0 + sh0, wt,         boff, lk8, acc);
      gemm_pass<2048>(Ab, 17 + p0,       wt + 16384, boff, lk8, acc);
      gemm_pass<2048>(Ab, 17 + p0 + sh2, wt + 32768, boff, lk8, acc);
      store_silu(Bb, p0, cbase, acc[0]);
      store_silu(Bb, p1, cbase, acc[1]);
    }
    __syncthreads();
    // 1x1: B -> silu -> residual add into A (masked)
    {
      acc[0] = bias_init(biasL, 5 + blk, cbase);
      acc[1] = acc[0];
      gemm_pass<2048>(Bb, p0, wpx + blk * 16384, boff, lk8, acc);
      resid_update(Ab, p0 + 17, cbase, acc[0], v0);
      resid_update(Ab, p1 + 17, cbase, acc[1], v1);
    }
    __syncthreads();
  }

  // ---- Conv0dResBlock ----
  {
    acc[0] = bias_init(biasL, 9, cbase);
    acc[1] = acc[0];
    gemm_pass<2048>(Ab, 17 + p0, ws + O_C1, boff, lk8, acc);
    store_silu(Bb, p0, cbase, acc[0]);
    store_silu(Bb, p1, cbase, acc[1]);
  }
  __syncthreads();
  {
    acc[0] = bias_init(biasL, 10, cbase);
    acc[1] = acc[0];
    gemm_pass<2048>(Bb, p0, ws + O_C2, boff, lk8, acc);
    resid_update(Ab, p0 + 17, cbase, acc[0], v0);
    resid_update(Ab, p1 + 17, cbase, acc[1], v1);
  }
  __syncthreads();

  // ---- final 1x1 (N=64, no silu): only ng 0..1 have channels ----
  if (ng < 2) {
    acc[0] = bias_init(biasL, 11, cbase);
    acc[1] = acc[0];
    gemm_pass<1024>(Ab, 17 + p0, ws + O_F, boff, lk8, acc);
  }
  __syncthreads();   // Bb (c2 gemm reads) done before stg overwrite
  float* stg = (float*)Bb;   // [64][225] fp32 = 57.6 KB
  if (ng < 2) {
#pragma unroll
    for (int mm = 0; mm < 2; ++mm) {
      int p = p0 + mm * 32;
      bool vm = mm ? v1 : v0;
      if (vm) {
        int y = (p >> 4) - 1, xx = p & 15;
        int pix = y * 15 + xx;
#pragma unroll
        for (int j = 0; j < 16; ++j) {
          int c = cbase + (j & 3) + 8 * (j >> 2);
          stg[c * 225 + pix] = acc[mm][j];
        }
      }
    }
  }
  __syncthreads();
  {
    size_t base = (size_t)bid * 14400;
    for (int i = tid; i < 14400; i += 1024)
      __builtin_nontemporal_store(stg[i], &out[base + i]);
  }
}

extern "C" void kernel_launch(void* const* d_in, const int* in_sizes, int n_in,
                              void* d_out, int out_size, void* d_ws, size_t ws_size,
                              hipStream_t stream) {
  (void)in_sizes; (void)n_in; (void)out_size;
  const float* x    = (const float*)d_in[0];
  const float* w_d0 = (const float*)d_in[1];
  const float* b_d0 = (const float*)d_in[2];
  const float* w_dc = (const float*)d_in[3];
  const float* b_dc = (const float*)d_in[4];
  const float* w_px = (const float*)d_in[5];
  const float* b_px = (const float*)d_in[6];
  const float* w_c1 = (const float*)d_in[7];
  const float* b_c1 = (const float*)d_in[8];
  const float* w_c2 = (const float*)d_in[9];
  const float* b_c2 = (const float*)d_in[10];
  const float* w_f  = (const float*)d_in[11];
  const float* b_f  = (const float*)d_in[12];
  float* out = (float*)d_out;
  _Float16* ws = (_Float16*)d_ws;
  if (ws_size < (size_t)W_TOTAL * sizeof(_Float16)) return;  // fail loudly

  wconv_kernel<<<(W_TOTAL + 255) / 256, 256, 0, stream>>>(w_d0, w_dc, w_px, w_c1, w_c2, w_f, ws);
  mixnet_kernel<<<4096, 1024, 0, stream>>>(x, ws, b_d0, b_dc, b_px, b_c1, b_c2, b_f, out);
}